// Round 1
// baseline (181.250 us; speedup 1.0000x reference)
//
#include <hip/hip_runtime.h>
#include <math.h>

// Chamfer distance, B=8, N=8192 both sides, fp32 in, fp32 scalar out.
//
// final = (sum over all 2*B*N query points of sqrt(max(min_sqdist, EPS))) / (2*B*N)
//
// Kernel 1: brute-force partial mins. 512 blocks x 256 threads.
//   Each block: one (dir, batch, query-chunk-of-1024, target-chunk-of-2048).
//   Q=4 queries per thread held in registers; targets staged in LDS as
//   padded float4 (one ds_read_b128 broadcast per target, shared by 4 queries
//   -> 28 VALU instrs per LDS instr: VALU-bound by design).
// Kernel 2: min across 4 target chunks + sqrt + per-block sum (512 blocks).
// Kernel 3: final sum of 512 partials, scale, write scalar.

#define NPTS   8192
#define NB     8
#define Q      4
#define TC     4                  // target chunks
#define BLOCK  256
#define TILE   512                // targets per LDS tile
#define QPB    (BLOCK * Q)        // 1024 queries per block
#define TOTALQ (2 * NB * NPTS)    // 131072
#define CHUNKT (NPTS / TC)        // 2048 targets per chunk
#define EPSV   1e-12f

__global__ __launch_bounds__(BLOCK) void chamfer_partial_min(
    const float* __restrict__ xyz1, const float* __restrict__ xyz2,
    float* __restrict__ partial)   // [TC][TOTALQ]
{
    const int bid = blockIdx.x;            // [0, 512)
    const int c   = bid & (TC - 1);        // target chunk
    const int qb  = bid >> 2;              // [0, 128) query-block
    const int dir = qb >> 6;               // 0: xyz1->xyz2, 1: xyz2->xyz1
    const int b   = (qb >> 3) & 7;
    const int qc  = qb & 7;                // query chunk of 1024 within batch

    const float* __restrict__ qsrc = (dir == 0) ? xyz1 : xyz2;
    const float* __restrict__ tsrc = (dir == 0) ? xyz2 : xyz1;

    const int tid = threadIdx.x;

    // Load Q query points into registers (coalesced-ish, once per kernel).
    float qx[Q], qy[Q], qz[Q], dmin[Q];
#pragma unroll
    for (int q = 0; q < Q; ++q) {
        const int i = qc * QPB + q * BLOCK + tid;
        const float* p = qsrc + ((size_t)b * NPTS + i) * 3;
        qx[q] = p[0];
        qy[q] = p[1];
        qz[q] = p[2];
        dmin[q] = 3.4e38f;
    }

    __shared__ float4 lds4[TILE];
    float* ldsf = (float*)lds4;

    const int tbase = c * CHUNKT;

    for (int t0 = 0; t0 < CHUNKT; t0 += TILE) {
        __syncthreads();
        // Stage TILE targets (TILE*3 floats) into LDS, padded to float4.
        const float* __restrict__ g = tsrc + ((size_t)b * NPTS + tbase + t0) * 3;
#pragma unroll
        for (int k = 0; k < (TILE * 3) / BLOCK; ++k) {
            const int f = k * BLOCK + tid;        // flat float index [0, 1536)
            const int tgt  = f / 3;
            const int comp = f - tgt * 3;
            ldsf[tgt * 4 + comp] = g[f];
        }
        __syncthreads();

#pragma unroll 4
        for (int j = 0; j < TILE; ++j) {
            const float4 tp = lds4[j];            // broadcast ds_read_b128
#pragma unroll
            for (int q = 0; q < Q; ++q) {
                const float dx = qx[q] - tp.x;
                const float dy = qy[q] - tp.y;
                const float dz = qz[q] - tp.z;
                const float d  = dx * dx + dy * dy + dz * dz;
                dmin[q] = fminf(dmin[q], d);
            }
        }
    }

    // Write exact per-chunk partial mins (each slot written by exactly one thread).
#pragma unroll
    for (int q = 0; q < Q; ++q) {
        const int gq = (dir * NB + b) * NPTS + qc * QPB + q * BLOCK + tid;
        partial[(size_t)c * TOTALQ + gq] = dmin[q];
    }
}

__global__ __launch_bounds__(BLOCK) void chamfer_reduce1(
    const float* __restrict__ partial,   // [TC][TOTALQ]
    float* __restrict__ sums)            // [TOTALQ/BLOCK] = [512]
{
    const int idx = blockIdx.x * BLOCK + threadIdx.x;   // [0, TOTALQ)
    float m = partial[idx];
#pragma unroll
    for (int cc = 1; cc < TC; ++cc)
        m = fminf(m, partial[(size_t)cc * TOTALQ + idx]);
    float val = sqrtf(fmaxf(m, EPSV));

    __shared__ float red[BLOCK];
    red[threadIdx.x] = val;
    __syncthreads();
    for (int s = BLOCK / 2; s > 0; s >>= 1) {
        if (threadIdx.x < s) red[threadIdx.x] += red[threadIdx.x + s];
        __syncthreads();
    }
    if (threadIdx.x == 0) sums[blockIdx.x] = red[0];
}

#define NSUMS (TOTALQ / BLOCK)   // 512

__global__ __launch_bounds__(NSUMS) void chamfer_finalize(
    const float* __restrict__ sums, float* __restrict__ out)
{
    __shared__ float red[NSUMS];
    red[threadIdx.x] = sums[threadIdx.x];
    __syncthreads();
    for (int s = NSUMS / 2; s > 0; s >>= 1) {
        if (threadIdx.x < s) red[threadIdx.x] += red[threadIdx.x + s];
        __syncthreads();
    }
    if (threadIdx.x == 0) out[0] = red[0] * (1.0f / (float)TOTALQ);
}

extern "C" void kernel_launch(void* const* d_in, const int* in_sizes, int n_in,
                              void* d_out, int out_size, void* d_ws, size_t ws_size,
                              hipStream_t stream) {
    const float* xyz1 = (const float*)d_in[0];
    const float* xyz2 = (const float*)d_in[1];
    float* out = (float*)d_out;

    float* partial = (float*)d_ws;                         // TC * TOTALQ floats = 2 MB
    float* sums    = partial + (size_t)TC * TOTALQ;        // 512 floats

    chamfer_partial_min<<<(2 * NB * NPTS / QPB) * TC, BLOCK, 0, stream>>>(xyz1, xyz2, partial);
    chamfer_reduce1<<<TOTALQ / BLOCK, BLOCK, 0, stream>>>(partial, sums);
    chamfer_finalize<<<1, NSUMS, 0, stream>>>(sums, out);
}

// Round 2
// 97.476 us; speedup vs baseline: 1.8594x; 1.8594x over previous
//
#include <hip/hip_runtime.h>
#include <math.h>

// Chamfer distance, B=8, N=8192 both sides, fp32 in, fp32 scalar out.
//
// d(q,t) = |q|^2 + |t|^2 - 2 q.t   ->  min_t d = |q|^2 + min_t (|t|^2 - 2 q.t)
//
// prep:        each cloud -> float4 (x, y, z, |p|^2) in ws       (O(N))
// chamfer_min: 512 blocks x 256 thr. Q=8 queries/thread in regs
//              (pre-scaled to -2x,-2y,-2z), 1024 targets staged in LDS as
//              float4; inner loop = 3 FMA/pair + min3 per 2 pairs
//              (~3.5 VALU/pair). Per-chunk result merged with atomicMin on
//              nonneg-float bit patterns (exact, order-independent).
// reduce1:     sqrt(max(min,EPS)) + per-256 block sums.
// finalize:    sum 512 partials, scale, write scalar.

#define NPTS   8192
#define NB     8
#define NPC    (NB * NPTS)        // 65536 points per cloud
#define Q      8
#define BLOCK  256
#define QPB    (BLOCK * Q)        // 2048 queries per block
#define TC     8                  // target chunks
#define CHUNKT (NPTS / TC)        // 1024 targets per chunk
#define TOTALQ (2 * NPC)          // 131072
#define EPSV   1e-12f

__global__ __launch_bounds__(BLOCK) void chamfer_prep(
    const float* __restrict__ src, float4* __restrict__ dst, int n)
{
    int i = blockIdx.x * BLOCK + threadIdx.x;
    if (i < n) {
        float x = src[3 * i], y = src[3 * i + 1], z = src[3 * i + 2];
        dst[i] = make_float4(x, y, z, fmaf(x, x, fmaf(y, y, z * z)));
    }
}

__global__ __launch_bounds__(BLOCK) void chamfer_min(
    const float4* __restrict__ t4,      // [2][NPC] transformed clouds
    unsigned* __restrict__ partial)     // [TOTALQ], preset to 0x7F7F7F7F
{
    const int bid = blockIdx.x;            // [0, 512)
    const int c   = bid & (TC - 1);        // target chunk
    const int qb  = bid >> 3;              // [0, 64) query block
    const int dir = qb >> 5;               // 0: xyz1->xyz2, 1: xyz2->xyz1
    const int b   = (qb >> 2) & 7;
    const int qc  = qb & 3;                // query chunk of QPB within batch

    const float4* __restrict__ qsrc = t4 + (size_t)dir * NPC + (size_t)b * NPTS;
    const float4* __restrict__ tsrc = t4 + (size_t)(1 - dir) * NPC
                                         + (size_t)b * NPTS + c * CHUNKT;
    const int tid = threadIdx.x;

    float qxn[Q], qyn[Q], qzn[Q], qn[Q], dmin[Q];
#pragma unroll
    for (int q = 0; q < Q; ++q) {
        float4 p = qsrc[qc * QPB + q * BLOCK + tid];
        qxn[q] = -2.0f * p.x;
        qyn[q] = -2.0f * p.y;
        qzn[q] = -2.0f * p.z;
        qn[q]  = p.w;
        dmin[q] = 3.4e38f;
    }

    __shared__ float4 lds[CHUNKT];          // 16 KB
#pragma unroll
    for (int k = 0; k < CHUNKT / BLOCK; ++k)
        lds[k * BLOCK + tid] = tsrc[k * BLOCK + tid];
    __syncthreads();

#pragma unroll 4
    for (int j = 0; j < CHUNKT; j += 2) {
        const float4 ta = lds[j];           // broadcast ds_read_b128
        const float4 tb = lds[j + 1];
#pragma unroll
        for (int q = 0; q < Q; ++q) {
            float v0 = fmaf(ta.x, qxn[q], ta.w);
            v0 = fmaf(ta.y, qyn[q], v0);
            v0 = fmaf(ta.z, qzn[q], v0);
            float v1 = fmaf(tb.x, qxn[q], tb.w);
            v1 = fmaf(tb.y, qyn[q], v1);
            v1 = fmaf(tb.z, qzn[q], v1);
            dmin[q] = fminf(dmin[q], fminf(v0, v1));   // -> v_min3_f32
        }
    }

    const int gqbase = (dir * NB + b) * NPTS + qc * QPB + tid;
#pragma unroll
    for (int q = 0; q < Q; ++q) {
        float v = fmaxf(dmin[q] + qn[q], 0.0f);        // nonneg -> uint order ok
        atomicMin(&partial[gqbase + q * BLOCK], __float_as_uint(v));
    }
}

__global__ __launch_bounds__(BLOCK) void chamfer_reduce1(
    const unsigned* __restrict__ partial,   // [TOTALQ]
    float* __restrict__ sums)               // [TOTALQ/BLOCK] = [512]
{
    const int idx = blockIdx.x * BLOCK + threadIdx.x;
    float m = __uint_as_float(partial[idx]);
    float val = sqrtf(fmaxf(m, EPSV));

    __shared__ float red[BLOCK];
    red[threadIdx.x] = val;
    __syncthreads();
    for (int s = BLOCK / 2; s > 0; s >>= 1) {
        if (threadIdx.x < s) red[threadIdx.x] += red[threadIdx.x + s];
        __syncthreads();
    }
    if (threadIdx.x == 0) sums[blockIdx.x] = red[0];
}

#define NSUMS (TOTALQ / BLOCK)   // 512

__global__ __launch_bounds__(NSUMS) void chamfer_finalize(
    const float* __restrict__ sums, float* __restrict__ out)
{
    __shared__ float red[NSUMS];
    red[threadIdx.x] = sums[threadIdx.x];
    __syncthreads();
    for (int s = NSUMS / 2; s > 0; s >>= 1) {
        if (threadIdx.x < s) red[threadIdx.x] += red[threadIdx.x + s];
        __syncthreads();
    }
    if (threadIdx.x == 0) out[0] = red[0] * (1.0f / (float)TOTALQ);
}

extern "C" void kernel_launch(void* const* d_in, const int* in_sizes, int n_in,
                              void* d_out, int out_size, void* d_ws, size_t ws_size,
                              hipStream_t stream) {
    const float* xyz1 = (const float*)d_in[0];
    const float* xyz2 = (const float*)d_in[1];
    float* out = (float*)d_out;

    float4*   t4      = (float4*)d_ws;                       // 2*NPC float4 = 2 MB
    unsigned* partial = (unsigned*)(t4 + 2 * (size_t)NPC);   // TOTALQ u32 = 512 KB
    float*    sums    = (float*)(partial + TOTALQ);          // 512 floats

    chamfer_prep<<<NPC / BLOCK, BLOCK, 0, stream>>>(xyz1, t4, NPC);
    chamfer_prep<<<NPC / BLOCK, BLOCK, 0, stream>>>(xyz2, t4 + NPC, NPC);

    // 0x7F7F7F7F as float = 3.39e38: valid "infinity" for nonneg-float uint-min.
    hipMemsetAsync(partial, 0x7F, TOTALQ * sizeof(unsigned), stream);

    chamfer_min<<<64 * TC, BLOCK, 0, stream>>>(t4, partial);
    chamfer_reduce1<<<TOTALQ / BLOCK, BLOCK, 0, stream>>>(partial, sums);
    chamfer_finalize<<<1, NSUMS, 0, stream>>>(sums, out);
}

// Round 3
// 68.505 us; speedup vs baseline: 2.6458x; 1.4229x over previous
//
#include <hip/hip_runtime.h>
#include <math.h>

// Chamfer distance via MFMA, B=8, N=8192, fp32 in, fp32 scalar out.
//
// d(q,t) = |q|^2 + |t|^2 - 2 q.t  ==  dot(A_row(q), B_col(t)) with K=5:
//   A_row = (-2x_q, -2y_q, -2z_q, 1, |q|^2),  B_col = (x_t, y_t, z_t, |t|^2, 1)
// in f16 (zero-padded to K=16).  One v_mfma_f32_32x32x16_f16 -> a 32x32 tile
// of complete squared distances in fp32; the only per-pair VALU work is the
// running row-min (v_min3, 0.5 lane-op/pair).
//
// Grid: 1024 blocks = dir(2) x batch(8) x rowblock(32) x colsplit(2).
// Block: 4 waves; wave owns 64 rows (2 strips of 32); iterates 4096 cols.
// B-forms built on the fly into LDS (512 cols/chunk, 8 KB). Partial row-mins
// merged via atomicMin on nonneg-float bit patterns (exact, deterministic).

#define NPTS   8192
#define NB     8
#define BLOCK  256
#define CHUNK  512
#define CS     2                   // col splits
#define COLS   (NPTS / CS)         // 4096 cols per block
#define TOTALQ (2 * NB * NPTS)     // 131072
#define EPSV   1e-12f

typedef _Float16 v8h  __attribute__((ext_vector_type(8)));
typedef float    v16f __attribute__((ext_vector_type(16)));

__global__ __launch_bounds__(BLOCK) void chamfer_mfma_min(
    const float* __restrict__ xyz1, const float* __restrict__ xyz2,
    unsigned* __restrict__ bits)       // [TOTALQ], preset to 0x7F7F7F7F
{
    const int bid = blockIdx.x;             // [0, 1024)
    const int cs  = bid & 1;
    const int rb  = (bid >> 1) & 31;
    const int b   = (bid >> 6) & 7;
    const int dir = (bid >> 9) & 1;

    const float* __restrict__ qsrc = (dir ? xyz2 : xyz1) + (size_t)b * NPTS * 3;
    const float* __restrict__ tsrc = (dir ? xyz1 : xyz2) + (size_t)b * NPTS * 3;

    const int tid  = threadIdx.x;
    const int lane = tid & 63;
    const int w    = tid >> 6;              // wave 0..3
    const int rowbase = rb * 256;

    // ---- A fragments: lanes<32 carry k=0..7 (the 5 live slots); lanes>=32
    // carry k=8..15 which are all zero, so their A frag is zero. ----
    v8h a0 = {}, a1 = {};
    if (lane < 32) {
        {
            const float* p = qsrc + (size_t)(rowbase + w * 64 + lane) * 3;
            _Float16 xh = (_Float16)p[0], yh = (_Float16)p[1], zh = (_Float16)p[2];
            float xf = (float)xh, yf = (float)yh, zf = (float)zh;
            float n = fmaf(xf, xf, fmaf(yf, yf, zf * zf));
            a0[0] = (_Float16)(-2.0f * xf);
            a0[1] = (_Float16)(-2.0f * yf);
            a0[2] = (_Float16)(-2.0f * zf);
            a0[3] = (_Float16)1.0f;
            a0[4] = (_Float16)n;
        }
        {
            const float* p = qsrc + (size_t)(rowbase + w * 64 + 32 + lane) * 3;
            _Float16 xh = (_Float16)p[0], yh = (_Float16)p[1], zh = (_Float16)p[2];
            float xf = (float)xh, yf = (float)yh, zf = (float)zh;
            float n = fmaf(xf, xf, fmaf(yf, yf, zf * zf));
            a1[0] = (_Float16)(-2.0f * xf);
            a1[1] = (_Float16)(-2.0f * yf);
            a1[2] = (_Float16)(-2.0f * zf);
            a1[3] = (_Float16)1.0f;
            a1[4] = (_Float16)n;
        }
    }

    float rm0[16], rm1[16];
#pragma unroll
    for (int r = 0; r < 16; ++r) { rm0[r] = 3.4e38f; rm1[r] = 3.4e38f; }

    __shared__ v8h bsh[CHUNK];              // 8 KB
    const v16f vzero = {};
    const int c31 = lane & 31;

    for (int ch = 0; ch < COLS / CHUNK; ++ch) {
        __syncthreads();
        const int colbase = cs * COLS + ch * CHUNK;
        for (int i = tid; i < CHUNK; i += BLOCK) {
            const float* p = tsrc + (size_t)(colbase + i) * 3;
            _Float16 xh = (_Float16)p[0], yh = (_Float16)p[1], zh = (_Float16)p[2];
            float xf = (float)xh, yf = (float)yh, zf = (float)zh;
            float n = fmaf(xf, xf, fmaf(yf, yf, zf * zf));
            v8h bv = {};
            bv[0] = xh; bv[1] = yh; bv[2] = zh;
            bv[3] = (_Float16)n; bv[4] = (_Float16)1.0f;
            bsh[i] = bv;
        }
        __syncthreads();

#pragma unroll
        for (int cc = 0; cc < CHUNK / 64; ++cc) {
            v8h b0 = bsh[cc * 64 + c31];
            v8h b1 = bsh[cc * 64 + 32 + c31];
            v16f acc00 = __builtin_amdgcn_mfma_f32_32x32x16_f16(a0, b0, vzero, 0, 0, 0);
            v16f acc01 = __builtin_amdgcn_mfma_f32_32x32x16_f16(a0, b1, vzero, 0, 0, 0);
            v16f acc10 = __builtin_amdgcn_mfma_f32_32x32x16_f16(a1, b0, vzero, 0, 0, 0);
            v16f acc11 = __builtin_amdgcn_mfma_f32_32x32x16_f16(a1, b1, vzero, 0, 0, 0);
#pragma unroll
            for (int r = 0; r < 16; ++r)
                rm0[r] = fminf(fminf(rm0[r], acc00[r]), acc01[r]);   // v_min3_f32
#pragma unroll
            for (int r = 0; r < 16; ++r)
                rm1[r] = fminf(fminf(rm1[r], acc10[r]), acc11[r]);
        }
    }

    // ---- finalize: butterfly row-min across the 32 lanes sharing each row,
    // then one atomicMin per row (nonneg-float uint order). ----
    unsigned* dst = bits + (size_t)(dir * NB + b) * NPTS + rowbase;
#pragma unroll
    for (int s = 0; s < 2; ++s) {
#pragma unroll
        for (int r = 0; r < 16; ++r) {
            float v = s ? rm1[r] : rm0[r];
            v = fminf(v, __shfl_xor(v, 1));
            v = fminf(v, __shfl_xor(v, 2));
            v = fminf(v, __shfl_xor(v, 4));
            v = fminf(v, __shfl_xor(v, 8));
            v = fminf(v, __shfl_xor(v, 16));
            if ((lane & 31) == 0) {
                int row_local = w * 64 + s * 32 + (r & 3) + 8 * (r >> 2) + 4 * (lane >> 5);
                atomicMin(dst + row_local, __float_as_uint(fmaxf(v, 0.0f)));
            }
        }
    }
}

__global__ __launch_bounds__(BLOCK) void chamfer_reduce1(
    const unsigned* __restrict__ bits,   // [TOTALQ]
    float* __restrict__ sums)            // [TOTALQ/BLOCK] = [512]
{
    const int idx = blockIdx.x * BLOCK + threadIdx.x;
    float m = __uint_as_float(bits[idx]);
    float val = sqrtf(fmaxf(m, EPSV));

    __shared__ float red[BLOCK];
    red[threadIdx.x] = val;
    __syncthreads();
    for (int s = BLOCK / 2; s > 0; s >>= 1) {
        if (threadIdx.x < s) red[threadIdx.x] += red[threadIdx.x + s];
        __syncthreads();
    }
    if (threadIdx.x == 0) sums[blockIdx.x] = red[0];
}

#define NSUMS (TOTALQ / BLOCK)   // 512

__global__ __launch_bounds__(NSUMS) void chamfer_finalize(
    const float* __restrict__ sums, float* __restrict__ out)
{
    __shared__ float red[NSUMS];
    red[threadIdx.x] = sums[threadIdx.x];
    __syncthreads();
    for (int s = NSUMS / 2; s > 0; s >>= 1) {
        if (threadIdx.x < s) red[threadIdx.x] += red[threadIdx.x + s];
        __syncthreads();
    }
    if (threadIdx.x == 0) out[0] = red[0] * (1.0f / (float)TOTALQ);
}

extern "C" void kernel_launch(void* const* d_in, const int* in_sizes, int n_in,
                              void* d_out, int out_size, void* d_ws, size_t ws_size,
                              hipStream_t stream) {
    const float* xyz1 = (const float*)d_in[0];
    const float* xyz2 = (const float*)d_in[1];
    float* out = (float*)d_out;

    unsigned* bitsbuf = (unsigned*)d_ws;                 // TOTALQ u32 = 512 KB
    float*    sums    = (float*)(bitsbuf + TOTALQ);      // 512 floats

    hipMemsetAsync(bitsbuf, 0x7F, TOTALQ * sizeof(unsigned), stream);

    chamfer_mfma_min<<<2 * NB * 32 * CS, BLOCK, 0, stream>>>(xyz1, xyz2, bitsbuf);
    chamfer_reduce1<<<TOTALQ / BLOCK, BLOCK, 0, stream>>>(bitsbuf, sums);
    chamfer_finalize<<<1, NSUMS, 0, stream>>>(sums, out);
}

// Round 4
// 65.394 us; speedup vs baseline: 2.7717x; 1.0476x over previous
//
#include <hip/hip_runtime.h>
#include <math.h>

// Chamfer distance via MFMA, B=8, N=8192, fp32 in, fp32 scalar out.
//
// d(q,t) = |q|^2 + |t|^2 - 2 q.t  ==  dot(A_row(q), B_col(t)) with K=5:
//   A_row = (-2x_q, -2y_q, -2z_q, 1, |q|^2),  B_col = (x_t, y_t, z_t, |t|^2, 1)
// in f16 (zero-padded to K=16).  One v_mfma_f32_32x32x16_f16 -> a 32x32 tile
// of complete squared distances in fp32.
//
// prep:   both clouds -> packed f16 form (x,y,z,n,1,0,0,0) + init bits buf.
// main:   1024 blocks = dir(2) x batch(8) x rowblock(32) x colsplit(2).
//         4 waves/block, wave owns 64 rows (2 strips of 32, processed
//         sequentially so only 2 acc tiles are live -> VGPR accumulators,
//         no v_accvgpr traffic). B staged in LDS as plain b128 copies.
// reduce: lane-min + atomicMin bits merge, then sqrt+sum+scale.

#define NPTS   8192
#define NB     8
#define NPC    (NB * NPTS)         // 65536
#define BLOCK  256
#define CHUNK  1024
#define CS     2                   // col splits
#define COLS   (NPTS / CS)         // 4096 cols per block
#define TOTALQ (2 * NPC)           // 131072
#define EPSV   1e-12f

typedef _Float16 v8h  __attribute__((ext_vector_type(8)));
typedef float    v16f __attribute__((ext_vector_type(16)));

__global__ __launch_bounds__(BLOCK) void chamfer_prep(
    const float* __restrict__ xyz1, const float* __restrict__ xyz2,
    v8h* __restrict__ form, unsigned* __restrict__ bits)
{
    const int gid = blockIdx.x * BLOCK + threadIdx.x;    // [0, TOTALQ)
    const float* __restrict__ src = (gid < NPC) ? xyz1 : xyz2;
    const int i = (gid < NPC) ? gid : gid - NPC;
    float x = src[3 * i], y = src[3 * i + 1], z = src[3 * i + 2];
    _Float16 xh = (_Float16)x, yh = (_Float16)y, zh = (_Float16)z;
    float xf = (float)xh, yf = (float)yh, zf = (float)zh;
    float n = fmaf(xf, xf, fmaf(yf, yf, zf * zf));
    v8h bv = {};
    bv[0] = xh; bv[1] = yh; bv[2] = zh;
    bv[3] = (_Float16)n; bv[4] = (_Float16)1.0f;
    form[gid] = bv;
    bits[gid] = 0x7F7F7F7FU;       // 3.39e38f: "+inf" for nonneg uint-min
}

__global__ __launch_bounds__(BLOCK) void chamfer_mfma_min(
    const v8h* __restrict__ form, unsigned* __restrict__ bits)
{
    const int bid = blockIdx.x;             // [0, 1024)
    const int cs  = bid & (CS - 1);
    const int rb  = (bid >> 1) & 31;
    const int b   = (bid >> 6) & 7;
    const int dir = (bid >> 9) & 1;

    const v8h* __restrict__ qf = form + (size_t)dir * NPC + (size_t)b * NPTS;
    const v8h* __restrict__ tf = form + (size_t)(1 - dir) * NPC
                                      + (size_t)b * NPTS + cs * COLS;

    const int tid  = threadIdx.x;
    const int lane = tid & 63;
    const int w    = tid >> 6;
    const int c31  = lane & 31;
    const int rowbase = rb * 256;

    // A fragments: lanes<32 carry k=0..7 (5 live slots); lanes>=32 carry
    // k=8..15 which are all zero.
    v8h a0 = {}, a1 = {};
    if (lane < 32) {
        const _Float16 m2 = (_Float16)(-2.0f);
        v8h f = qf[rowbase + w * 64 + lane];
        a0[0] = m2 * f[0]; a0[1] = m2 * f[1]; a0[2] = m2 * f[2];
        a0[3] = (_Float16)1.0f; a0[4] = f[3];
        f = qf[rowbase + w * 64 + 32 + lane];
        a1[0] = m2 * f[0]; a1[1] = m2 * f[1]; a1[2] = m2 * f[2];
        a1[3] = (_Float16)1.0f; a1[4] = f[3];
    }

    float rm0[16], rm1[16];
#pragma unroll
    for (int r = 0; r < 16; ++r) { rm0[r] = 3.4e38f; rm1[r] = 3.4e38f; }

    __shared__ v8h bsh[CHUNK];              // 16 KB
    const v16f vzero = {};

    for (int ch = 0; ch < COLS / CHUNK; ++ch) {
        __syncthreads();
        const v8h* __restrict__ g = tf + ch * CHUNK;
#pragma unroll
        for (int k = 0; k < CHUNK / BLOCK; ++k)
            bsh[k * BLOCK + tid] = g[k * BLOCK + tid];   // b128 in, b128 out
        __syncthreads();

#pragma unroll
        for (int cc = 0; cc < CHUNK / 64; ++cc) {
            const v8h b0 = bsh[cc * 64 + c31];           // broadcast b128
            const v8h b1 = bsh[cc * 64 + 32 + c31];
            {
                v16f p = __builtin_amdgcn_mfma_f32_32x32x16_f16(a0, b0, vzero, 0, 0, 0);
                v16f q = __builtin_amdgcn_mfma_f32_32x32x16_f16(a0, b1, vzero, 0, 0, 0);
#pragma unroll
                for (int r = 0; r < 16; ++r)
                    rm0[r] = fminf(fminf(rm0[r], p[r]), q[r]);   // v_min3_f32
            }
            {
                v16f p = __builtin_amdgcn_mfma_f32_32x32x16_f16(a1, b0, vzero, 0, 0, 0);
                v16f q = __builtin_amdgcn_mfma_f32_32x32x16_f16(a1, b1, vzero, 0, 0, 0);
#pragma unroll
                for (int r = 0; r < 16; ++r)
                    rm1[r] = fminf(fminf(rm1[r], p[r]), q[r]);
            }
        }
    }

    // Butterfly row-min across the 32 lanes sharing each row, then one
    // atomicMin per row (nonneg-float uint order; exact, deterministic).
    unsigned* dst = bits + (size_t)(dir * NB + b) * NPTS + rowbase;
#pragma unroll
    for (int s = 0; s < 2; ++s) {
#pragma unroll
        for (int r = 0; r < 16; ++r) {
            float v = s ? rm1[r] : rm0[r];
            v = fminf(v, __shfl_xor(v, 1));
            v = fminf(v, __shfl_xor(v, 2));
            v = fminf(v, __shfl_xor(v, 4));
            v = fminf(v, __shfl_xor(v, 8));
            v = fminf(v, __shfl_xor(v, 16));
            if ((lane & 31) == 0) {
                int row_local = w * 64 + s * 32 + (r & 3) + 8 * (r >> 2) + 4 * (lane >> 5);
                atomicMin(dst + row_local, __float_as_uint(fmaxf(v, 0.0f)));
            }
        }
    }
}

__global__ __launch_bounds__(BLOCK) void chamfer_reduce1(
    const unsigned* __restrict__ bits,   // [TOTALQ]
    float* __restrict__ sums)            // [512]
{
    const int idx = blockIdx.x * BLOCK + threadIdx.x;
    float m = __uint_as_float(bits[idx]);
    float val = sqrtf(fmaxf(m, EPSV));

    __shared__ float red[BLOCK];
    red[threadIdx.x] = val;
    __syncthreads();
    for (int s = BLOCK / 2; s > 0; s >>= 1) {
        if (threadIdx.x < s) red[threadIdx.x] += red[threadIdx.x + s];
        __syncthreads();
    }
    if (threadIdx.x == 0) sums[blockIdx.x] = red[0];
}

#define NSUMS (TOTALQ / BLOCK)   // 512

__global__ __launch_bounds__(NSUMS) void chamfer_finalize(
    const float* __restrict__ sums, float* __restrict__ out)
{
    __shared__ float red[NSUMS];
    red[threadIdx.x] = sums[threadIdx.x];
    __syncthreads();
    for (int s = NSUMS / 2; s > 0; s >>= 1) {
        if (threadIdx.x < s) red[threadIdx.x] += red[threadIdx.x + s];
        __syncthreads();
    }
    if (threadIdx.x == 0) out[0] = red[0] * (1.0f / (float)TOTALQ);
}

extern "C" void kernel_launch(void* const* d_in, const int* in_sizes, int n_in,
                              void* d_out, int out_size, void* d_ws, size_t ws_size,
                              hipStream_t stream) {
    const float* xyz1 = (const float*)d_in[0];
    const float* xyz2 = (const float*)d_in[1];
    float* out = (float*)d_out;

    v8h*      formbuf = (v8h*)d_ws;                      // TOTALQ v8h = 2 MB
    unsigned* bitsbuf = (unsigned*)(formbuf + TOTALQ);   // TOTALQ u32 = 512 KB
    float*    sums    = (float*)(bitsbuf + TOTALQ);      // 512 floats

    chamfer_prep<<<TOTALQ / BLOCK, BLOCK, 0, stream>>>(xyz1, xyz2, formbuf, bitsbuf);
    chamfer_mfma_min<<<2 * NB * 32 * CS, BLOCK, 0, stream>>>(formbuf, bitsbuf);
    chamfer_reduce1<<<TOTALQ / BLOCK, BLOCK, 0, stream>>>(bitsbuf, sums);
    chamfer_finalize<<<1, NSUMS, 0, stream>>>(sums, out);
}

// Round 5
// 48.902 us; speedup vs baseline: 3.7064x; 1.3372x over previous
//
#include <hip/hip_runtime.h>
#include <math.h>

// Chamfer distance via MFMA, B=8, N=8192, fp32 in, fp32 scalar out.
//
// d(q,t) = |q|^2 + |t|^2 - 2 q.t  ==  dot(A_row(q), B_col(t)) with K=5:
//   A_row = (-2x_q, -2y_q, -2z_q, 1, |q|^2),  B_col = (x_t, y_t, z_t, |t|^2, 1)
// in f16 (zero-padded to K=16).  One v_mfma_f32_32x32x16_f16 -> a 32x32 tile
// of complete squared distances in fp32.
//
// prep:   both clouds -> packed f16 form (x,y,z,n,1,0,0,0) + init bits buf.
// main:   1024 blocks = dir(2) x batch(8) x rowblock(32) x colsplit(2).
//         4 waves/block, wave owns 64 rows (2 strips of 32, sequential so
//         only 2 acc tiles live).  __launch_bounds__(256,4) -> 128 VGPR
//         budget so accumulators stay in VGPRs (no v_accvgpr traffic; the
//         min3 reduction reads MFMA results directly).
// reduce: lane-min + atomicMin bits merge, then sqrt+sum+scale.

#define NPTS   8192
#define NB     8
#define NPC    (NB * NPTS)         // 65536
#define BLOCK  256
#define CHUNK  1024
#define CS     2                   // col splits
#define COLS   (NPTS / CS)         // 4096 cols per block
#define TOTALQ (2 * NPC)           // 131072
#define EPSV   1e-12f

typedef _Float16 v8h  __attribute__((ext_vector_type(8)));
typedef float    v16f __attribute__((ext_vector_type(16)));

__global__ __launch_bounds__(BLOCK) void chamfer_prep(
    const float* __restrict__ xyz1, const float* __restrict__ xyz2,
    v8h* __restrict__ form, unsigned* __restrict__ bits)
{
    const int gid = blockIdx.x * BLOCK + threadIdx.x;    // [0, TOTALQ)
    const float* __restrict__ src = (gid < NPC) ? xyz1 : xyz2;
    const int i = (gid < NPC) ? gid : gid - NPC;
    float x = src[3 * i], y = src[3 * i + 1], z = src[3 * i + 2];
    _Float16 xh = (_Float16)x, yh = (_Float16)y, zh = (_Float16)z;
    float xf = (float)xh, yf = (float)yh, zf = (float)zh;
    float n = fmaf(xf, xf, fmaf(yf, yf, zf * zf));
    v8h bv = {};
    bv[0] = xh; bv[1] = yh; bv[2] = zh;
    bv[3] = (_Float16)n; bv[4] = (_Float16)1.0f;
    form[gid] = bv;
    bits[gid] = 0x7F7F7F7FU;       // 3.39e38f: "+inf" for nonneg uint-min
}

__global__ __launch_bounds__(BLOCK, 4) void chamfer_mfma_min(
    const v8h* __restrict__ form, unsigned* __restrict__ bits)
{
    const int bid = blockIdx.x;             // [0, 1024)
    const int cs  = bid & (CS - 1);
    const int rb  = (bid >> 1) & 31;
    const int b   = (bid >> 6) & 7;
    const int dir = (bid >> 9) & 1;

    const v8h* __restrict__ qf = form + (size_t)dir * NPC + (size_t)b * NPTS;
    const v8h* __restrict__ tf = form + (size_t)(1 - dir) * NPC
                                      + (size_t)b * NPTS + cs * COLS;

    const int tid  = threadIdx.x;
    const int lane = tid & 63;
    const int w    = tid >> 6;
    const int c31  = lane & 31;
    const int rowbase = rb * 256;

    // A fragments: lanes<32 carry k=0..7 (5 live slots); lanes>=32 carry
    // k=8..15 which are all zero.
    v8h a0 = {}, a1 = {};
    if (lane < 32) {
        const _Float16 m2 = (_Float16)(-2.0f);
        v8h f = qf[rowbase + w * 64 + lane];
        a0[0] = m2 * f[0]; a0[1] = m2 * f[1]; a0[2] = m2 * f[2];
        a0[3] = (_Float16)1.0f; a0[4] = f[3];
        f = qf[rowbase + w * 64 + 32 + lane];
        a1[0] = m2 * f[0]; a1[1] = m2 * f[1]; a1[2] = m2 * f[2];
        a1[3] = (_Float16)1.0f; a1[4] = f[3];
    }

    float rm0[16], rm1[16];
#pragma unroll
    for (int r = 0; r < 16; ++r) { rm0[r] = 3.4e38f; rm1[r] = 3.4e38f; }

    __shared__ v8h bsh[CHUNK];              // 16 KB
    const v16f vzero = {};

    for (int ch = 0; ch < COLS / CHUNK; ++ch) {
        __syncthreads();
        const v8h* __restrict__ g = tf + ch * CHUNK;
#pragma unroll
        for (int k = 0; k < CHUNK / BLOCK; ++k)
            bsh[k * BLOCK + tid] = g[k * BLOCK + tid];   // b128 in, b128 out
        __syncthreads();

#pragma unroll
        for (int cc = 0; cc < CHUNK / 64; ++cc) {
            const v8h b0 = bsh[cc * 64 + c31];           // broadcast b128
            const v8h b1 = bsh[cc * 64 + 32 + c31];
            {
                v16f p = __builtin_amdgcn_mfma_f32_32x32x16_f16(a0, b0, vzero, 0, 0, 0);
                v16f q = __builtin_amdgcn_mfma_f32_32x32x16_f16(a0, b1, vzero, 0, 0, 0);
#pragma unroll
                for (int r = 0; r < 16; ++r)
                    rm0[r] = fminf(fminf(rm0[r], p[r]), q[r]);   // v_min3_f32
            }
            {
                v16f p = __builtin_amdgcn_mfma_f32_32x32x16_f16(a1, b0, vzero, 0, 0, 0);
                v16f q = __builtin_amdgcn_mfma_f32_32x32x16_f16(a1, b1, vzero, 0, 0, 0);
#pragma unroll
                for (int r = 0; r < 16; ++r)
                    rm1[r] = fminf(fminf(rm1[r], p[r]), q[r]);
            }
        }
    }

    // Butterfly row-min across the 32 lanes sharing each row, then one
    // atomicMin per row (nonneg-float uint order; exact, deterministic).
    unsigned* dst = bits + (size_t)(dir * NB + b) * NPTS + rowbase;
#pragma unroll
    for (int s = 0; s < 2; ++s) {
#pragma unroll
        for (int r = 0; r < 16; ++r) {
            float v = s ? rm1[r] : rm0[r];
            v = fminf(v, __shfl_xor(v, 1));
            v = fminf(v, __shfl_xor(v, 2));
            v = fminf(v, __shfl_xor(v, 4));
            v = fminf(v, __shfl_xor(v, 8));
            v = fminf(v, __shfl_xor(v, 16));
            if ((lane & 31) == 0) {
                int row_local = w * 64 + s * 32 + (r & 3) + 8 * (r >> 2) + 4 * (lane >> 5);
                atomicMin(dst + row_local, __float_as_uint(fmaxf(v, 0.0f)));
            }
        }
    }
}

__global__ __launch_bounds__(BLOCK) void chamfer_reduce1(
    const unsigned* __restrict__ bits,   // [TOTALQ]
    float* __restrict__ sums)            // [512]
{
    const int idx = blockIdx.x * BLOCK + threadIdx.x;
    float m = __uint_as_float(bits[idx]);
    float val = sqrtf(fmaxf(m, EPSV));

    __shared__ float red[BLOCK];
    red[threadIdx.x] = val;
    __syncthreads();
    for (int s = BLOCK / 2; s > 0; s >>= 1) {
        if (threadIdx.x < s) red[threadIdx.x] += red[threadIdx.x + s];
        __syncthreads();
    }
    if (threadIdx.x == 0) sums[blockIdx.x] = red[0];
}

#define NSUMS (TOTALQ / BLOCK)   // 512

__global__ __launch_bounds__(NSUMS) void chamfer_finalize(
    const float* __restrict__ sums, float* __restrict__ out)
{
    __shared__ float red[NSUMS];
    red[threadIdx.x] = sums[threadIdx.x];
    __syncthreads();
    for (int s = NSUMS / 2; s > 0; s >>= 1) {
        if (threadIdx.x < s) red[threadIdx.x] += red[threadIdx.x + s];
        __syncthreads();
    }
    if (threadIdx.x == 0) out[0] = red[0] * (1.0f / (float)TOTALQ);
}

extern "C" void kernel_launch(void* const* d_in, const int* in_sizes, int n_in,
                              void* d_out, int out_size, void* d_ws, size_t ws_size,
                              hipStream_t stream) {
    const float* xyz1 = (const float*)d_in[0];
    const float* xyz2 = (const float*)d_in[1];
    float* out = (float*)d_out;

    v8h*      formbuf = (v8h*)d_ws;                      // TOTALQ v8h = 2 MB
    unsigned* bitsbuf = (unsigned*)(formbuf + TOTALQ);   // TOTALQ u32 = 512 KB
    float*    sums    = (float*)(bitsbuf + TOTALQ);      // 512 floats

    chamfer_prep<<<TOTALQ / BLOCK, BLOCK, 0, stream>>>(xyz1, xyz2, formbuf, bitsbuf);
    chamfer_mfma_min<<<2 * NB * 32 * CS, BLOCK, 0, stream>>>(formbuf, bitsbuf);
    chamfer_reduce1<<<TOTALQ / BLOCK, BLOCK, 0, stream>>>(bitsbuf, sums);
    chamfer_finalize<<<1, NSUMS, 0, stream>>>(sums, out);
}